// Round 7
// baseline (813.726 us; speedup 1.0000x reference)
//
#include <hip/hip_runtime.h>
#include <math.h>

// ---------------------------------------------------------------------------
// BitNet-style MNIST forward, fully fused, STRICT-FP32, tie-neutralized
// act-quant (R14) + R15/R16 layout work + R17 (barrier-free per-wave fc) +
// R19/R20 (30.4kB LDS, launch_bounds) + R21:
//  * 3 IMAGES PER BLOCK, fc on 3 CONCURRENT WAVES. R20's occupancy counter
//    (25% ~= 8 waves avg) proved the single-wave serial fc tail is 2-4x the
//    conv phase per block: block lifetime was Tc(4 waves) + Tf(1 wave),
//    Tf ~ 2-4*Tc. Now: conv A-D runs 3x sequentially (all threads, same
//    barriers, per-image arithmetic IDENTICAL), stage D writes s_v96[im];
//    then waves 0/1/2 each run the R17 barrier-free fc for one image
//    concurrently. Per-block: 3(Tc+Tf) -> 3Tc+Tf.
//  * LDS = 29,184 conv + 3x1,184 fc = 32,736 B -> rounds to 32,768 (512-B
//    granule) -> still exactly 5 blocks/CU. NO array aliasing (R18 lesson).
//  * Grid = ceil(8192/3) = 2731; tail block guards img >= nimg; guards
//    never skip barriers.
// ---------------------------------------------------------------------------

#define OFF_W1   0        // 16 oc x 12      = 192   ([oc][k], k padded 9->12)
#define OFF_W1B  192      // 16 oc x 16 x 12 = 3072  ([oc][ic*12+k])
#define OFF_W2   3264     // 96*1*12*12 = 13824 (TRANSPOSED: [k=144][96 oc])
#define OFF_F1   17088    // 64*96      = 6144  (TRANSPOSED: [k=96][64 o])
#define OFF_F2   23232    // 64*64      = 4096  (TRANSPOSED: [k=64][64 o])
#define OFF_F3   27328    // 64*64      = 4096  (TRANSPOSED: [k=64][64 o])
#define OFF_FL   31424    // 10*64      = 640   (TRANSPOSED: [k=64][10 o])

#define EPS_TIE  3e-5f    // code-units half-width of the tie band

// Tie-neutralized quantized real value for v >= 0 (post-ReLU / normed >= 0).
__device__ __forceinline__ float quantq(float v, float s) {
    const float u  = __fmul_rn(v, s);
    const float fl = floorf(u);
    const float fr = __fsub_rn(u, fl);                 // exact
    float q;
    if (fabsf(__fsub_rn(fr, 0.5f)) < EPS_TIE) q = __fadd_rn(fl, 0.5f);
    else                                      q = rintf(u);
    q = fminf(q, 127.f);
    return __fdiv_rn(q, s);
}

// numpy pairwise leaf (n <= 128): 8 unrolled accumulators over |p[i]|.
__device__ __forceinline__ float leaf_abs_sum(const float* __restrict__ p, int n) {
    float r[8];
    #pragma unroll
    for (int j = 0; j < 8; ++j) r[j] = fabsf(p[j]);
    const int nb = n & ~7;
    for (int i = 8; i < nb; i += 8) {
        #pragma unroll
        for (int j = 0; j < 8; ++j) r[j] = __fadd_rn(r[j], fabsf(p[i + j]));
    }
    float c = __fadd_rn(__fadd_rn(__fadd_rn(r[0], r[1]), __fadd_rn(r[2], r[3])),
                        __fadd_rn(__fadd_rn(r[4], r[5]), __fadd_rn(r[6], r[7])));
    for (int i = nb; i < n; ++i) c = __fadd_rn(c, fabsf(p[i]));
    return c;
}

// ---------------------------------------------------------------------------
// Weight quantization: 7 blocks, one per tensor. Values identical; only
// destination layouts changed (see R16 header).
// ---------------------------------------------------------------------------
__global__ __launch_bounds__(256) void wq_kernel(
    const float* __restrict__ w1, const float* __restrict__ w1b,
    const float* __restrict__ w2, const float* __restrict__ f1,
    const float* __restrict__ f2, const float* __restrict__ f3,
    const float* __restrict__ fl, float* __restrict__ ws)
{
    __shared__ float red[256];
    __shared__ float ls[128];
    const int blk = blockIdx.x, t = threadIdx.x;

    const float* src; int n; int mode; int off; int K; int W;
    switch (blk) {
        case 0:  src = w1;  n = 144;   mode = 0; off = OFF_W1;  K = 0;   W = 0;  break;
        case 1:  src = w1b; n = 2304;  mode = 0; off = OFF_W1B; K = 0;   W = 0;  break;
        case 2:  src = w2;  n = 13824; mode = 1; off = OFF_W2;  K = 144; W = 96; break;
        case 3:  src = f1;  n = 6144;  mode = 1; off = OFF_F1;  K = 96;  W = 64; break;
        case 4:  src = f2;  n = 4096;  mode = 1; off = OFF_F2;  K = 64;  W = 64; break;
        case 5:  src = f3;  n = 4096;  mode = 1; off = OFF_F3;  K = 64;  W = 64; break;
        default: src = fl;  n = 640;   mode = 1; off = OFF_FL;  K = 64;  W = 10; break;
    }

    if (mode == 0) {
        float p = 0.f;
        for (int i = t; i < n; i += 256) p = fmaxf(p, fabsf(src[i]));
        red[t] = p;
        __syncthreads();
        for (int s = 128; s > 0; s >>= 1) {
            if (t < s) red[t] = fmaxf(red[t], red[t + s]);
            __syncthreads();
        }
        const float s = __fdiv_rn(127.0f, fmaxf(red[0], 1e-5f));
        for (int i = t; i < n; i += 256) {
            float q = rintf(__fmul_rn(src[i], s));
            q = fminf(fmaxf(q, -128.f), 127.f);
            int d;
            if (blk == 0) d = (i / 9) * 12 + (i % 9);
            else          { const int oc = i / 144, k = i % 144;
                            d = oc * 192 + (k / 9) * 12 + (k % 9); }
            ws[off + d] = __fdiv_rn(q, s);
        }
    } else {
        int nleaf, loff, lsz;
        switch (n) {
            case 13824: nleaf = 128; loff = (t >> 1) * 216 + (t & 1) * 104;
                        lsz = (t & 1) ? 112 : 104; break;
            case 6144:  nleaf = 64;  loff = t * 96;  lsz = 96;  break;
            case 4096:  nleaf = 32;  loff = t * 128; lsz = 128; break;
            default:    nleaf = 8;   loff = t * 80;  lsz = 80;  break;  // 640
        }
        if (t < nleaf) ls[t] = leaf_abs_sum(src + loff, lsz);
        __syncthreads();
        for (int m = nleaf >> 1; m >= 1; m >>= 1) {
            float v = 0.f;
            if (t < m) v = __fadd_rn(ls[2 * t], ls[2 * t + 1]);
            __syncthreads();
            if (t < m) ls[t] = v;
            __syncthreads();
        }
        const float alpha = __fdiv_rn(ls[0], (float)n);
        for (int i = t; i < n; i += 256) {
            const float w = src[i];
            const float sg = (w > 0.f) ? 1.f : ((w < 0.f) ? -1.f : 0.f);
            const int d = (i % K) * W + (i / K);
            ws[off + d] = __fmul_rn(sg, alpha);
        }
    }
}

// ---------------------------------------------------------------------------
// Fused forward: one block (256 threads) per 3 images, strict fp32.
// LDS total 32,736 B -> 5 blocks/CU.
// ---------------------------------------------------------------------------
__global__ __launch_bounds__(256, 8) void fused_kernel(
    const float* __restrict__ x, const float* __restrict__ ws,
    float* __restrict__ out, int nimg)
{
    __shared__ __align__(16) float s_x[16][20];        //  1280 B
    __shared__ __align__(16) float s_h1[16][14][20];   // 17920 B
    __shared__ float s_h2[16 * 156];                   //  9984 B (stride-13 rows)
    __shared__ float s_v96[3][96];                     //  1152 B
    __shared__ float s_t96[3][96];                     //  1152 B
    __shared__ float s_q[3][96];                       //  1152 B
    __shared__ float s_r8[3][8];                       //    96 B

    const int img0 = blockIdx.x * 3;
    const int t = threadIdx.x;

    // ======================= conv phases: 3 images sequential ==============
    #pragma unroll 1
    for (int im = 0; im < 3; ++im) {
        const int img = img0 + im;
        const bool ok = (img < nimg);

        // ---- Stage A: input act-quant (accumulation-free -> hard round) ----
        if (ok) {
            const float v = x[img * 256 + t];
            float m = fabsf(v);
            #pragma unroll
            for (int msk = 8; msk >= 1; msk >>= 1) m = fmaxf(m, __shfl_xor(m, msk, 16));
            const float s = __fdiv_rn(127.0f, fmaxf(m, 1e-5f));
            float q = rintf(__fmul_rn(v, s));
            q = fminf(fmaxf(q, -128.f), 127.f);
            s_x[t >> 4][t & 15] = __fdiv_rn(q, s);
        }
        __syncthreads();

        // ---- Stage B: conv1 (1->16, 3x3) + ReLU + row quant ----
        if (ok && t < 224) {
            const int oc = t / 14, oh = t % 14;
            const float* __restrict__ wg = ws + OFF_W1 + oc * 12;
            const float4 wv0 = *(const float4*)&wg[0];
            const float4 wv1 = *(const float4*)&wg[4];
            const float  w8  = wg[8];
            const float wr[9] = {wv0.x, wv0.y, wv0.z, wv0.w,
                                 wv1.x, wv1.y, wv1.z, wv1.w, w8};
            float acc[14];
            #pragma unroll
            for (int ow = 0; ow < 14; ++ow) acc[ow] = 0.f;
            #pragma unroll
            for (int kh = 0; kh < 3; ++kh) {
                float A[16];
                *(float4*)&A[0]  = *(const float4*)&s_x[oh + kh][0];
                *(float4*)&A[4]  = *(const float4*)&s_x[oh + kh][4];
                *(float4*)&A[8]  = *(const float4*)&s_x[oh + kh][8];
                *(float4*)&A[12] = *(const float4*)&s_x[oh + kh][12];
                #pragma unroll
                for (int kw = 0; kw < 3; ++kw) {
                    const float wk = wr[kh * 3 + kw];
                    #pragma unroll
                    for (int ow = 0; ow < 14; ++ow)
                        acc[ow] = __fmaf_rn(A[ow + kw], wk, acc[ow]);
                }
            }
            float mx = 0.f;
            #pragma unroll
            for (int ow = 0; ow < 14; ++ow) { acc[ow] = fmaxf(acc[ow], 0.f); mx = fmaxf(mx, acc[ow]); }
            const float s = __fdiv_rn(127.0f, fmaxf(mx, 1e-5f));
            float q[14];
            #pragma unroll
            for (int ow = 0; ow < 14; ++ow) q[ow] = quantq(acc[ow], s);
            *(float4*)&s_h1[oc][oh][0]  = *(const float4*)&q[0];
            *(float4*)&s_h1[oc][oh][4]  = *(const float4*)&q[4];
            *(float4*)&s_h1[oc][oh][8]  = *(const float4*)&q[8];
            *(float2*)&s_h1[oc][oh][12] = *(const float2*)&q[12];
        }
        __syncthreads();

        // ---- Stage C: conv1b (16->16, 3x3) + ReLU + row quant ----
        if (ok && t < 192) {
            const int oc = t / 12, oh = t % 12;
            const float* __restrict__ wg = ws + OFF_W1B + oc * 192;
            float acc[12];
            #pragma unroll
            for (int i = 0; i < 12; ++i) acc[i] = 0.f;
            for (int ic = 0; ic < 16; ++ic) {
                const float4 wv0 = *(const float4*)&wg[ic * 12];
                const float4 wv1 = *(const float4*)&wg[ic * 12 + 4];
                const float  w8  = wg[ic * 12 + 8];
                const float wr[9] = {wv0.x, wv0.y, wv0.z, wv0.w,
                                     wv1.x, wv1.y, wv1.z, wv1.w, w8};
                #pragma unroll
                for (int kh = 0; kh < 3; ++kh) {
                    float A[14];
                    *(float4*)&A[0]  = *(const float4*)&s_h1[ic][oh + kh][0];
                    *(float4*)&A[4]  = *(const float4*)&s_h1[ic][oh + kh][4];
                    *(float4*)&A[8]  = *(const float4*)&s_h1[ic][oh + kh][8];
                    *(float2*)&A[12] = *(const float2*)&s_h1[ic][oh + kh][12];
                    #pragma unroll
                    for (int kw = 0; kw < 3; ++kw) {
                        const float w = wr[kh * 3 + kw];
                        #pragma unroll
                        for (int ow = 0; ow < 12; ++ow)
                            acc[ow] = __fmaf_rn(A[ow + kw], w, acc[ow]);
                    }
                }
            }
            float mx = 0.f;
            #pragma unroll
            for (int ow = 0; ow < 12; ++ow) { acc[ow] = fmaxf(acc[ow], 0.f); mx = fmaxf(mx, acc[ow]); }
            const float s = __fdiv_rn(127.0f, fmaxf(mx, 1e-5f));
            const int hb = oc * 156 + oh * 13;
            #pragma unroll
            for (int ow = 0; ow < 12; ++ow)
                s_h2[hb + ow] = quantq(acc[ow], s);
        }
        __syncthreads();

        // ---- Stage D: conv2 grouped binary (16 g x 6 oc, 12x12) + ReLU ----
        if (ok && t < 96) {
            const int g = t / 6;
            const float* __restrict__ wp = ws + OFF_W2;  // [k=144][96 oc]
            float acc = 0.f;
            #pragma unroll
            for (int r = 0; r < 12; ++r) {
                const int hb = g * 156 + r * 13;
                #pragma unroll
                for (int c = 0; c < 12; ++c)
                    acc = __fmaf_rn(s_h2[hb + c], wp[(r * 12 + c) * 96 + t], acc);
            }
            s_v96[im][t] = fmaxf(acc, 0.f);
        }
        __syncthreads();
    }

    // ============ fc section: waves 0/1/2, one image each, no barriers ======
    const int w = t >> 6;      // wave id = fc image slot
    const int l = t & 63;      // lane within wave
    if (w >= 3) return;        // wave 3 retires
    const int img = img0 + w;
    if (img >= nimg) return;

    // ---- Stage E: fc1 (96->64) ----
    float u;   // current activation vector element (lane l holds element l)
    {
        const float va = s_v96[w][l];
        const float vb = (l < 32) ? s_v96[w][64 + l] : 0.f;
        s_t96[w][l] = __fmul_rn(va, va);
        if (l < 32) s_t96[w][64 + l] = __fmul_rn(vb, vb);
        if (l < 8) {
            float r = s_t96[w][l];
            for (int i = 8; i < 96; i += 8) r = __fadd_rn(r, s_t96[w][i + l]);
            s_r8[w][l] = r;
        }
        // all lanes redundantly compute the tree -> identical bits, no broadcast
        const float c = __fadd_rn(
            __fadd_rn(__fadd_rn(s_r8[w][0], s_r8[w][1]), __fadd_rn(s_r8[w][2], s_r8[w][3])),
            __fadd_rn(__fadd_rn(s_r8[w][4], s_r8[w][5]), __fadd_rn(s_r8[w][6], s_r8[w][7])));
        const float mean = __fdiv_rn(c, 96.0f);
        const float bc1 = __fdiv_rn(1.0f, __fsqrt_rn(__fadd_rn(mean, 1e-6f)));
        const float n0 = __fmul_rn(va, bc1);
        const float n1 = __fmul_rn(vb, bc1);       // valid for l<32
        float m = n0;
        if (l < 32) m = fmaxf(m, n1);
        #pragma unroll
        for (int msk = 32; msk >= 1; msk >>= 1) m = fmaxf(m, __shfl_xor(m, msk, 64));
        const float s2 = __fdiv_rn(127.0f, fmaxf(m, 1e-5f));
        s_q[w][l] = quantq(n0, s2);
        if (l < 32) s_q[w][64 + l] = quantq(n1, s2);
        const float* __restrict__ wp = ws + OFF_F1;  // [k=96][64 o]
        float acc = 0.f;
        for (int k = 0; k < 96; ++k) acc = __fmaf_rn(s_q[w][k], wp[k * 64 + l], acc);
        u = fmaxf(acc, 0.f);
    }

    // ---- Stages F,G: fc2, fc3 (64->64) ----
    #pragma unroll 1
    for (int stage = 0; stage < 2; ++stage) {
        const int woff = stage == 0 ? OFF_F2 : OFF_F3;
        s_t96[w][l] = __fmul_rn(u, u);
        if (l < 8) {
            float r = s_t96[w][l];
            for (int i = 8; i < 64; i += 8) r = __fadd_rn(r, s_t96[w][i + l]);
            s_r8[w][l] = r;
        }
        const float c = __fadd_rn(
            __fadd_rn(__fadd_rn(s_r8[w][0], s_r8[w][1]), __fadd_rn(s_r8[w][2], s_r8[w][3])),
            __fadd_rn(__fadd_rn(s_r8[w][4], s_r8[w][5]), __fadd_rn(s_r8[w][6], s_r8[w][7])));
        const float mean = __fdiv_rn(c, 64.0f);
        const float bc1 = __fdiv_rn(1.0f, __fsqrt_rn(__fadd_rn(mean, 1e-6f)));
        const float n0 = __fmul_rn(u, bc1);
        float m = n0;
        #pragma unroll
        for (int msk = 32; msk >= 1; msk >>= 1) m = fmaxf(m, __shfl_xor(m, msk, 64));
        const float s2 = __fdiv_rn(127.0f, fmaxf(m, 1e-5f));
        s_q[w][l] = quantq(n0, s2);
        const float* __restrict__ wp = ws + woff;    // [k=64][64 o]
        float acc = 0.f;
        for (int k = 0; k < 64; ++k) acc = __fmaf_rn(s_q[w][k], wp[k * 64 + l], acc);
        u = fmaxf(acc, 0.f);
    }

    // ---- Stage H: fcl (64->10), no ReLU ----
    {
        s_t96[w][l] = __fmul_rn(u, u);
        if (l < 8) {
            float r = s_t96[w][l];
            for (int i = 8; i < 64; i += 8) r = __fadd_rn(r, s_t96[w][i + l]);
            s_r8[w][l] = r;
        }
        const float c = __fadd_rn(
            __fadd_rn(__fadd_rn(s_r8[w][0], s_r8[w][1]), __fadd_rn(s_r8[w][2], s_r8[w][3])),
            __fadd_rn(__fadd_rn(s_r8[w][4], s_r8[w][5]), __fadd_rn(s_r8[w][6], s_r8[w][7])));
        const float mean = __fdiv_rn(c, 64.0f);
        const float bc1 = __fdiv_rn(1.0f, __fsqrt_rn(__fadd_rn(mean, 1e-6f)));
        const float n0 = __fmul_rn(u, bc1);
        float m = n0;
        #pragma unroll
        for (int msk = 32; msk >= 1; msk >>= 1) m = fmaxf(m, __shfl_xor(m, msk, 64));
        const float s2 = __fdiv_rn(127.0f, fmaxf(m, 1e-5f));
        s_q[w][l] = quantq(n0, s2);
        const int to = (l < 10) ? l : 9;             // clamp: avoid OOB reads
        const float* __restrict__ wp = ws + OFF_FL;  // [k=64][10 o]
        float acc = 0.f;
        for (int k = 0; k < 64; ++k) acc = __fmaf_rn(s_q[w][k], wp[k * 10 + to], acc);
        if (l < 10) out[img * 10 + l] = acc;
    }
}

extern "C" void kernel_launch(void* const* d_in, const int* in_sizes, int n_in,
                              void* d_out, int out_size, void* d_ws, size_t ws_size,
                              hipStream_t stream) {
    const float* x   = (const float*)d_in[0];
    const float* w1  = (const float*)d_in[1];
    const float* w1b = (const float*)d_in[2];
    const float* w2  = (const float*)d_in[3];
    const float* f1  = (const float*)d_in[4];
    const float* f2  = (const float*)d_in[5];
    const float* f3  = (const float*)d_in[6];
    const float* fl  = (const float*)d_in[7];
    float* out = (float*)d_out;
    float* ws  = (float*)d_ws;

    const int B = in_sizes[0] / 256;  // 8192
    const int nblk = (B + 2) / 3;

    wq_kernel<<<7, 256, 0, stream>>>(w1, w1b, w2, f1, f2, f3, fl, ws);
    fused_kernel<<<nblk, 256, 0, stream>>>(x, ws, out, B);
}

// Round 8
// 223.881 us; speedup vs baseline: 3.6346x; 3.6346x over previous
//
#include <hip/hip_runtime.h>
#include <math.h>

// ---------------------------------------------------------------------------
// BitNet-style MNIST forward, STRICT-FP32, tie-neutralized act-quant (R14),
// R15/R16 layouts, R19/R20 LDS+bounds. R22: PHASE-SPLIT KERNELS.
//  * R21 (3 images/block, fc on 3 waves in one kernel) exploded VGPR 68->180
//    (bound dropped, spills) -> 756us. Theory (fc tail = 2-4x conv, proven by
//    R20's 8-waves-avg occupancy) retained; vehicle replaced:
//  * conv_kernel: R20 stages A-D VERBATIM (1 image/block, proven codegen),
//    stage D -> global v96 slab at ws+32768 (3.1MB; ~6MB round-trip traffic
//    is noise). No fc tail: 4 waves busy whole lifetime, 5 blocks/CU.
//  * fc_kernel: R17 barrier-free per-wave fc, 4 waves/block = 4 images/block,
//    LDS 3,200B, low VGPR -> 8 waves/SIMD = 32 waves/CU of independent
//    latency chains (the TLP the serial fc needed).
//  * Per-image arithmetic identical everywhere -> absmax unchanged.
// ---------------------------------------------------------------------------

#define OFF_W1   0        // 16 oc x 12      = 192   ([oc][k], k padded 9->12)
#define OFF_W1B  192      // 16 oc x 16 x 12 = 3072  ([oc][ic*12+k])
#define OFF_W2   3264     // 96*1*12*12 = 13824 (TRANSPOSED: [k=144][96 oc])
#define OFF_F1   17088    // 64*96      = 6144  (TRANSPOSED: [k=96][64 o])
#define OFF_F2   23232    // 64*64      = 4096  (TRANSPOSED: [k=64][64 o])
#define OFF_F3   27328    // 64*64      = 4096  (TRANSPOSED: [k=64][64 o])
#define OFF_FL   31424    // 10*64      = 640   (TRANSPOSED: [k=64][10 o])
#define OFF_V96  32768    // 8192 x 96 activation slab (phase handoff)

#define EPS_TIE  3e-5f    // code-units half-width of the tie band

// Tie-neutralized quantized real value for v >= 0 (post-ReLU / normed >= 0).
__device__ __forceinline__ float quantq(float v, float s) {
    const float u  = __fmul_rn(v, s);
    const float fl = floorf(u);
    const float fr = __fsub_rn(u, fl);                 // exact
    float q;
    if (fabsf(__fsub_rn(fr, 0.5f)) < EPS_TIE) q = __fadd_rn(fl, 0.5f);
    else                                      q = rintf(u);
    q = fminf(q, 127.f);
    return __fdiv_rn(q, s);
}

// numpy pairwise leaf (n <= 128): 8 unrolled accumulators over |p[i]|.
__device__ __forceinline__ float leaf_abs_sum(const float* __restrict__ p, int n) {
    float r[8];
    #pragma unroll
    for (int j = 0; j < 8; ++j) r[j] = fabsf(p[j]);
    const int nb = n & ~7;
    for (int i = 8; i < nb; i += 8) {
        #pragma unroll
        for (int j = 0; j < 8; ++j) r[j] = __fadd_rn(r[j], fabsf(p[i + j]));
    }
    float c = __fadd_rn(__fadd_rn(__fadd_rn(r[0], r[1]), __fadd_rn(r[2], r[3])),
                        __fadd_rn(__fadd_rn(r[4], r[5]), __fadd_rn(r[6], r[7])));
    for (int i = nb; i < n; ++i) c = __fadd_rn(c, fabsf(p[i]));
    return c;
}

// ---------------------------------------------------------------------------
// Weight quantization: 7 blocks, one per tensor. (unchanged from R16)
// ---------------------------------------------------------------------------
__global__ __launch_bounds__(256) void wq_kernel(
    const float* __restrict__ w1, const float* __restrict__ w1b,
    const float* __restrict__ w2, const float* __restrict__ f1,
    const float* __restrict__ f2, const float* __restrict__ f3,
    const float* __restrict__ fl, float* __restrict__ ws)
{
    __shared__ float red[256];
    __shared__ float ls[128];
    const int blk = blockIdx.x, t = threadIdx.x;

    const float* src; int n; int mode; int off; int K; int W;
    switch (blk) {
        case 0:  src = w1;  n = 144;   mode = 0; off = OFF_W1;  K = 0;   W = 0;  break;
        case 1:  src = w1b; n = 2304;  mode = 0; off = OFF_W1B; K = 0;   W = 0;  break;
        case 2:  src = w2;  n = 13824; mode = 1; off = OFF_W2;  K = 144; W = 96; break;
        case 3:  src = f1;  n = 6144;  mode = 1; off = OFF_F1;  K = 96;  W = 64; break;
        case 4:  src = f2;  n = 4096;  mode = 1; off = OFF_F2;  K = 64;  W = 64; break;
        case 5:  src = f3;  n = 4096;  mode = 1; off = OFF_F3;  K = 64;  W = 64; break;
        default: src = fl;  n = 640;   mode = 1; off = OFF_FL;  K = 64;  W = 10; break;
    }

    if (mode == 0) {
        float p = 0.f;
        for (int i = t; i < n; i += 256) p = fmaxf(p, fabsf(src[i]));
        red[t] = p;
        __syncthreads();
        for (int s = 128; s > 0; s >>= 1) {
            if (t < s) red[t] = fmaxf(red[t], red[t + s]);
            __syncthreads();
        }
        const float s = __fdiv_rn(127.0f, fmaxf(red[0], 1e-5f));
        for (int i = t; i < n; i += 256) {
            float q = rintf(__fmul_rn(src[i], s));
            q = fminf(fmaxf(q, -128.f), 127.f);
            int d;
            if (blk == 0) d = (i / 9) * 12 + (i % 9);
            else          { const int oc = i / 144, k = i % 144;
                            d = oc * 192 + (k / 9) * 12 + (k % 9); }
            ws[off + d] = __fdiv_rn(q, s);
        }
    } else {
        int nleaf, loff, lsz;
        switch (n) {
            case 13824: nleaf = 128; loff = (t >> 1) * 216 + (t & 1) * 104;
                        lsz = (t & 1) ? 112 : 104; break;
            case 6144:  nleaf = 64;  loff = t * 96;  lsz = 96;  break;
            case 4096:  nleaf = 32;  loff = t * 128; lsz = 128; break;
            default:    nleaf = 8;   loff = t * 80;  lsz = 80;  break;  // 640
        }
        if (t < nleaf) ls[t] = leaf_abs_sum(src + loff, lsz);
        __syncthreads();
        for (int m = nleaf >> 1; m >= 1; m >>= 1) {
            float v = 0.f;
            if (t < m) v = __fadd_rn(ls[2 * t], ls[2 * t + 1]);
            __syncthreads();
            if (t < m) ls[t] = v;
            __syncthreads();
        }
        const float alpha = __fdiv_rn(ls[0], (float)n);
        for (int i = t; i < n; i += 256) {
            const float w = src[i];
            const float sg = (w > 0.f) ? 1.f : ((w < 0.f) ? -1.f : 0.f);
            const int d = (i % K) * W + (i / K);
            ws[off + d] = __fmul_rn(sg, alpha);
        }
    }
}

// ---------------------------------------------------------------------------
// conv_kernel: stages A-D, one image per block (R20 verbatim), writes v96
// to the global handoff slab. LDS 29,184 B -> 5 blocks/CU.
// ---------------------------------------------------------------------------
__global__ __launch_bounds__(256, 8) void conv_kernel(
    const float* __restrict__ x, float* __restrict__ ws)
{
    __shared__ __align__(16) float s_x[16][20];        //  1280 B
    __shared__ __align__(16) float s_h1[16][14][20];   // 17920 B
    __shared__ float s_h2[16 * 156];                   //  9984 B (stride-13 rows)

    const int b = blockIdx.x;
    const int t = threadIdx.x;

    // ---- Stage A: input act-quant (accumulation-free -> hard round) ----
    {
        const float v = x[b * 256 + t];
        float m = fabsf(v);
        #pragma unroll
        for (int msk = 8; msk >= 1; msk >>= 1) m = fmaxf(m, __shfl_xor(m, msk, 16));
        const float s = __fdiv_rn(127.0f, fmaxf(m, 1e-5f));
        float q = rintf(__fmul_rn(v, s));
        q = fminf(fmaxf(q, -128.f), 127.f);
        s_x[t >> 4][t & 15] = __fdiv_rn(q, s);
    }
    __syncthreads();

    // ---- Stage B: conv1 (1->16, 3x3) + ReLU + row quant ----
    if (t < 224) {
        const int oc = t / 14, oh = t % 14;
        const float* __restrict__ wg = ws + OFF_W1 + oc * 12;
        const float4 wv0 = *(const float4*)&wg[0];
        const float4 wv1 = *(const float4*)&wg[4];
        const float  w8  = wg[8];
        const float wr[9] = {wv0.x, wv0.y, wv0.z, wv0.w,
                             wv1.x, wv1.y, wv1.z, wv1.w, w8};
        float acc[14];
        #pragma unroll
        for (int ow = 0; ow < 14; ++ow) acc[ow] = 0.f;
        #pragma unroll
        for (int kh = 0; kh < 3; ++kh) {
            float A[16];
            *(float4*)&A[0]  = *(const float4*)&s_x[oh + kh][0];
            *(float4*)&A[4]  = *(const float4*)&s_x[oh + kh][4];
            *(float4*)&A[8]  = *(const float4*)&s_x[oh + kh][8];
            *(float4*)&A[12] = *(const float4*)&s_x[oh + kh][12];
            #pragma unroll
            for (int kw = 0; kw < 3; ++kw) {
                const float wk = wr[kh * 3 + kw];
                #pragma unroll
                for (int ow = 0; ow < 14; ++ow)
                    acc[ow] = __fmaf_rn(A[ow + kw], wk, acc[ow]);
            }
        }
        float mx = 0.f;
        #pragma unroll
        for (int ow = 0; ow < 14; ++ow) { acc[ow] = fmaxf(acc[ow], 0.f); mx = fmaxf(mx, acc[ow]); }
        const float s = __fdiv_rn(127.0f, fmaxf(mx, 1e-5f));
        float q[14];
        #pragma unroll
        for (int ow = 0; ow < 14; ++ow) q[ow] = quantq(acc[ow], s);
        *(float4*)&s_h1[oc][oh][0]  = *(const float4*)&q[0];
        *(float4*)&s_h1[oc][oh][4]  = *(const float4*)&q[4];
        *(float4*)&s_h1[oc][oh][8]  = *(const float4*)&q[8];
        *(float2*)&s_h1[oc][oh][12] = *(const float2*)&q[12];
    }
    __syncthreads();

    // ---- Stage C: conv1b (16->16, 3x3) + ReLU + row quant ----
    if (t < 192) {
        const int oc = t / 12, oh = t % 12;
        const float* __restrict__ wg = ws + OFF_W1B + oc * 192;
        float acc[12];
        #pragma unroll
        for (int i = 0; i < 12; ++i) acc[i] = 0.f;
        for (int ic = 0; ic < 16; ++ic) {
            const float4 wv0 = *(const float4*)&wg[ic * 12];
            const float4 wv1 = *(const float4*)&wg[ic * 12 + 4];
            const float  w8  = wg[ic * 12 + 8];
            const float wr[9] = {wv0.x, wv0.y, wv0.z, wv0.w,
                                 wv1.x, wv1.y, wv1.z, wv1.w, w8};
            #pragma unroll
            for (int kh = 0; kh < 3; ++kh) {
                float A[14];
                *(float4*)&A[0]  = *(const float4*)&s_h1[ic][oh + kh][0];
                *(float4*)&A[4]  = *(const float4*)&s_h1[ic][oh + kh][4];
                *(float4*)&A[8]  = *(const float4*)&s_h1[ic][oh + kh][8];
                *(float2*)&A[12] = *(const float2*)&s_h1[ic][oh + kh][12];
                #pragma unroll
                for (int kw = 0; kw < 3; ++kw) {
                    const float w = wr[kh * 3 + kw];
                    #pragma unroll
                    for (int ow = 0; ow < 12; ++ow)
                        acc[ow] = __fmaf_rn(A[ow + kw], w, acc[ow]);
                }
            }
        }
        float mx = 0.f;
        #pragma unroll
        for (int ow = 0; ow < 12; ++ow) { acc[ow] = fmaxf(acc[ow], 0.f); mx = fmaxf(mx, acc[ow]); }
        const float s = __fdiv_rn(127.0f, fmaxf(mx, 1e-5f));
        const int hb = oc * 156 + oh * 13;
        #pragma unroll
        for (int ow = 0; ow < 12; ++ow)
            s_h2[hb + ow] = quantq(acc[ow], s);
    }
    __syncthreads();

    // ---- Stage D: conv2 grouped binary (16 g x 6 oc, 12x12) + ReLU ----
    if (t < 96) {
        const int g = t / 6;
        const float* __restrict__ wp = ws + OFF_W2;  // [k=144][96 oc]
        float acc = 0.f;
        #pragma unroll
        for (int r = 0; r < 12; ++r) {
            const int hb = g * 156 + r * 13;
            #pragma unroll
            for (int c = 0; c < 12; ++c)
                acc = __fmaf_rn(s_h2[hb + c], wp[(r * 12 + c) * 96 + t], acc);
        }
        ws[OFF_V96 + b * 96 + t] = fmaxf(acc, 0.f);   // global handoff
    }
}

// ---------------------------------------------------------------------------
// fc_kernel: 4 waves per block, each wave runs the barrier-free R17 fc chain
// for one image. LDS 3,200 B; occupancy VGPR-capped (32 waves/CU target).
// ---------------------------------------------------------------------------
__global__ __launch_bounds__(256) void fc_kernel(
    const float* __restrict__ ws, float* __restrict__ out, int nimg)
{
    __shared__ float s_t96[4][96];
    __shared__ float s_q[4][96];
    __shared__ float s_r8[4][8];

    const int t = threadIdx.x;
    const int w = t >> 6;      // wave id = image slot
    const int l = t & 63;      // lane within wave
    const int img = blockIdx.x * 4 + w;
    if (img >= nimg) return;

    const float* __restrict__ v96 = ws + OFF_V96 + img * 96;

    // ---- Stage E: fc1 (96->64) ----
    float u;   // current activation vector element (lane l holds element l)
    {
        const float va = v96[l];
        const float vb = (l < 32) ? v96[64 + l] : 0.f;
        s_t96[w][l] = __fmul_rn(va, va);
        if (l < 32) s_t96[w][64 + l] = __fmul_rn(vb, vb);
        if (l < 8) {
            float r = s_t96[w][l];
            for (int i = 8; i < 96; i += 8) r = __fadd_rn(r, s_t96[w][i + l]);
            s_r8[w][l] = r;
        }
        // all lanes redundantly compute the tree -> identical bits, no broadcast
        const float c = __fadd_rn(
            __fadd_rn(__fadd_rn(s_r8[w][0], s_r8[w][1]), __fadd_rn(s_r8[w][2], s_r8[w][3])),
            __fadd_rn(__fadd_rn(s_r8[w][4], s_r8[w][5]), __fadd_rn(s_r8[w][6], s_r8[w][7])));
        const float mean = __fdiv_rn(c, 96.0f);
        const float bc1 = __fdiv_rn(1.0f, __fsqrt_rn(__fadd_rn(mean, 1e-6f)));
        const float n0 = __fmul_rn(va, bc1);
        const float n1 = __fmul_rn(vb, bc1);       // valid for l<32
        float m = n0;
        if (l < 32) m = fmaxf(m, n1);
        #pragma unroll
        for (int msk = 32; msk >= 1; msk >>= 1) m = fmaxf(m, __shfl_xor(m, msk, 64));
        const float s2 = __fdiv_rn(127.0f, fmaxf(m, 1e-5f));
        s_q[w][l] = quantq(n0, s2);
        if (l < 32) s_q[w][64 + l] = quantq(n1, s2);
        const float* __restrict__ wp = ws + OFF_F1;  // [k=96][64 o]
        float acc = 0.f;
        for (int k = 0; k < 96; ++k) acc = __fmaf_rn(s_q[w][k], wp[k * 64 + l], acc);
        u = fmaxf(acc, 0.f);
    }

    // ---- Stages F,G: fc2, fc3 (64->64) ----
    #pragma unroll 1
    for (int stage = 0; stage < 2; ++stage) {
        const int woff = stage == 0 ? OFF_F2 : OFF_F3;
        s_t96[w][l] = __fmul_rn(u, u);
        if (l < 8) {
            float r = s_t96[w][l];
            for (int i = 8; i < 64; i += 8) r = __fadd_rn(r, s_t96[w][i + l]);
            s_r8[w][l] = r;
        }
        const float c = __fadd_rn(
            __fadd_rn(__fadd_rn(s_r8[w][0], s_r8[w][1]), __fadd_rn(s_r8[w][2], s_r8[w][3])),
            __fadd_rn(__fadd_rn(s_r8[w][4], s_r8[w][5]), __fadd_rn(s_r8[w][6], s_r8[w][7])));
        const float mean = __fdiv_rn(c, 64.0f);
        const float bc1 = __fdiv_rn(1.0f, __fsqrt_rn(__fadd_rn(mean, 1e-6f)));
        const float n0 = __fmul_rn(u, bc1);
        float m = n0;
        #pragma unroll
        for (int msk = 32; msk >= 1; msk >>= 1) m = fmaxf(m, __shfl_xor(m, msk, 64));
        const float s2 = __fdiv_rn(127.0f, fmaxf(m, 1e-5f));
        s_q[w][l] = quantq(n0, s2);
        const float* __restrict__ wp = ws + woff;    // [k=64][64 o]
        float acc = 0.f;
        for (int k = 0; k < 64; ++k) acc = __fmaf_rn(s_q[w][k], wp[k * 64 + l], acc);
        u = fmaxf(acc, 0.f);
    }

    // ---- Stage H: fcl (64->10), no ReLU ----
    {
        s_t96[w][l] = __fmul_rn(u, u);
        if (l < 8) {
            float r = s_t96[w][l];
            for (int i = 8; i < 64; i += 8) r = __fadd_rn(r, s_t96[w][i + l]);
            s_r8[w][l] = r;
        }
        const float c = __fadd_rn(
            __fadd_rn(__fadd_rn(s_r8[w][0], s_r8[w][1]), __fadd_rn(s_r8[w][2], s_r8[w][3])),
            __fadd_rn(__fadd_rn(s_r8[w][4], s_r8[w][5]), __fadd_rn(s_r8[w][6], s_r8[w][7])));
        const float mean = __fdiv_rn(c, 64.0f);
        const float bc1 = __fdiv_rn(1.0f, __fsqrt_rn(__fadd_rn(mean, 1e-6f)));
        const float n0 = __fmul_rn(u, bc1);
        float m = n0;
        #pragma unroll
        for (int msk = 32; msk >= 1; msk >>= 1) m = fmaxf(m, __shfl_xor(m, msk, 64));
        const float s2 = __fdiv_rn(127.0f, fmaxf(m, 1e-5f));
        s_q[w][l] = quantq(n0, s2);
        const int to = (l < 10) ? l : 9;             // clamp: avoid OOB reads
        const float* __restrict__ wp = ws + OFF_FL;  // [k=64][10 o]
        float acc = 0.f;
        for (int k = 0; k < 64; ++k) acc = __fmaf_rn(s_q[w][k], wp[k * 10 + to], acc);
        if (l < 10) out[img * 10 + l] = acc;
    }
}

extern "C" void kernel_launch(void* const* d_in, const int* in_sizes, int n_in,
                              void* d_out, int out_size, void* d_ws, size_t ws_size,
                              hipStream_t stream) {
    const float* x   = (const float*)d_in[0];
    const float* w1  = (const float*)d_in[1];
    const float* w1b = (const float*)d_in[2];
    const float* w2  = (const float*)d_in[3];
    const float* f1  = (const float*)d_in[4];
    const float* f2  = (const float*)d_in[5];
    const float* f3  = (const float*)d_in[6];
    const float* fl  = (const float*)d_in[7];
    float* out = (float*)d_out;
    float* ws  = (float*)d_ws;

    const int B = in_sizes[0] / 256;  // 8192

    wq_kernel<<<7, 256, 0, stream>>>(w1, w1b, w2, f1, f2, f3, fl, ws);
    conv_kernel<<<B, 256, 0, stream>>>(x, ws);
    fc_kernel<<<(B + 3) / 4, 256, 0, stream>>>(ws, out, B);
}

// Round 9
// 222.861 us; speedup vs baseline: 3.6513x; 1.0046x over previous
//
#include <hip/hip_runtime.h>
#include <math.h>

// ---------------------------------------------------------------------------
// BitNet-style MNIST forward, STRICT-FP32, tie-neutralized act-quant (R14),
// R15/R16 layouts, R22 phase-split kernels. R23: fc SHUFFLE REDUCE.
//  * fc_kernel's per-stage mean-reduce was a serial LDS round trip (store +
//    11 dependent stride-8 loads + 8-load tree ~= 1500 cy/stage x4). Replaced
//    with ds_bpermute/shfl chains that reproduce the EXACT numpy-pairwise
//    order: lane l computes r8[l&7] with the same serial left-assoc adds
//    (shfl latency ~35cy vs LDS ~120cy), then the 8->1 tree as 3 shfl_xor
//    butterfly steps (bit-exact: fadd_rn is commutative, each lane's swapped
//    grouping gives identical bits). s_t96/s_r8 deleted (fc LDS 1,536 B).
//  * conv_kernel / wq_kernel VERBATIM from R22 (proven: conv 136us @ 80%
//    VALUBusy ~ issue-bound; do not touch).
// ---------------------------------------------------------------------------

#define OFF_W1   0        // 16 oc x 12      = 192   ([oc][k], k padded 9->12)
#define OFF_W1B  192      // 16 oc x 16 x 12 = 3072  ([oc][ic*12+k])
#define OFF_W2   3264     // 96*1*12*12 = 13824 (TRANSPOSED: [k=144][96 oc])
#define OFF_F1   17088    // 64*96      = 6144  (TRANSPOSED: [k=96][64 o])
#define OFF_F2   23232    // 64*64      = 4096  (TRANSPOSED: [k=64][64 o])
#define OFF_F3   27328    // 64*64      = 4096  (TRANSPOSED: [k=64][64 o])
#define OFF_FL   31424    // 10*64      = 640   (TRANSPOSED: [k=64][10 o])
#define OFF_V96  32768    // 8192 x 96 activation slab (phase handoff)

#define EPS_TIE  3e-5f    // code-units half-width of the tie band

// Tie-neutralized quantized real value for v >= 0 (post-ReLU / normed >= 0).
__device__ __forceinline__ float quantq(float v, float s) {
    const float u  = __fmul_rn(v, s);
    const float fl = floorf(u);
    const float fr = __fsub_rn(u, fl);                 // exact
    float q;
    if (fabsf(__fsub_rn(fr, 0.5f)) < EPS_TIE) q = __fadd_rn(fl, 0.5f);
    else                                      q = rintf(u);
    q = fminf(q, 127.f);
    return __fdiv_rn(q, s);
}

// numpy pairwise leaf (n <= 128): 8 unrolled accumulators over |p[i]|.
__device__ __forceinline__ float leaf_abs_sum(const float* __restrict__ p, int n) {
    float r[8];
    #pragma unroll
    for (int j = 0; j < 8; ++j) r[j] = fabsf(p[j]);
    const int nb = n & ~7;
    for (int i = 8; i < nb; i += 8) {
        #pragma unroll
        for (int j = 0; j < 8; ++j) r[j] = __fadd_rn(r[j], fabsf(p[i + j]));
    }
    float c = __fadd_rn(__fadd_rn(__fadd_rn(r[0], r[1]), __fadd_rn(r[2], r[3])),
                        __fadd_rn(__fadd_rn(r[4], r[5]), __fadd_rn(r[6], r[7])));
    for (int i = nb; i < n; ++i) c = __fadd_rn(c, fabsf(p[i]));
    return c;
}

// ---------------------------------------------------------------------------
// Weight quantization: 7 blocks, one per tensor. (unchanged from R16/R22)
// ---------------------------------------------------------------------------
__global__ __launch_bounds__(256) void wq_kernel(
    const float* __restrict__ w1, const float* __restrict__ w1b,
    const float* __restrict__ w2, const float* __restrict__ f1,
    const float* __restrict__ f2, const float* __restrict__ f3,
    const float* __restrict__ fl, float* __restrict__ ws)
{
    __shared__ float red[256];
    __shared__ float ls[128];
    const int blk = blockIdx.x, t = threadIdx.x;

    const float* src; int n; int mode; int off; int K; int W;
    switch (blk) {
        case 0:  src = w1;  n = 144;   mode = 0; off = OFF_W1;  K = 0;   W = 0;  break;
        case 1:  src = w1b; n = 2304;  mode = 0; off = OFF_W1B; K = 0;   W = 0;  break;
        case 2:  src = w2;  n = 13824; mode = 1; off = OFF_W2;  K = 144; W = 96; break;
        case 3:  src = f1;  n = 6144;  mode = 1; off = OFF_F1;  K = 96;  W = 64; break;
        case 4:  src = f2;  n = 4096;  mode = 1; off = OFF_F2;  K = 64;  W = 64; break;
        case 5:  src = f3;  n = 4096;  mode = 1; off = OFF_F3;  K = 64;  W = 64; break;
        default: src = fl;  n = 640;   mode = 1; off = OFF_FL;  K = 64;  W = 10; break;
    }

    if (mode == 0) {
        float p = 0.f;
        for (int i = t; i < n; i += 256) p = fmaxf(p, fabsf(src[i]));
        red[t] = p;
        __syncthreads();
        for (int s = 128; s > 0; s >>= 1) {
            if (t < s) red[t] = fmaxf(red[t], red[t + s]);
            __syncthreads();
        }
        const float s = __fdiv_rn(127.0f, fmaxf(red[0], 1e-5f));
        for (int i = t; i < n; i += 256) {
            float q = rintf(__fmul_rn(src[i], s));
            q = fminf(fmaxf(q, -128.f), 127.f);
            int d;
            if (blk == 0) d = (i / 9) * 12 + (i % 9);
            else          { const int oc = i / 144, k = i % 144;
                            d = oc * 192 + (k / 9) * 12 + (k % 9); }
            ws[off + d] = __fdiv_rn(q, s);
        }
    } else {
        int nleaf, loff, lsz;
        switch (n) {
            case 13824: nleaf = 128; loff = (t >> 1) * 216 + (t & 1) * 104;
                        lsz = (t & 1) ? 112 : 104; break;
            case 6144:  nleaf = 64;  loff = t * 96;  lsz = 96;  break;
            case 4096:  nleaf = 32;  loff = t * 128; lsz = 128; break;
            default:    nleaf = 8;   loff = t * 80;  lsz = 80;  break;  // 640
        }
        if (t < nleaf) ls[t] = leaf_abs_sum(src + loff, lsz);
        __syncthreads();
        for (int m = nleaf >> 1; m >= 1; m >>= 1) {
            float v = 0.f;
            if (t < m) v = __fadd_rn(ls[2 * t], ls[2 * t + 1]);
            __syncthreads();
            if (t < m) ls[t] = v;
            __syncthreads();
        }
        const float alpha = __fdiv_rn(ls[0], (float)n);
        for (int i = t; i < n; i += 256) {
            const float w = src[i];
            const float sg = (w > 0.f) ? 1.f : ((w < 0.f) ? -1.f : 0.f);
            const int d = (i % K) * W + (i / K);
            ws[off + d] = __fmul_rn(sg, alpha);
        }
    }
}

// ---------------------------------------------------------------------------
// conv_kernel: stages A-D, one image per block (R22 verbatim), writes v96
// to the global handoff slab. LDS 29,184 B -> 5 blocks/CU.
// ---------------------------------------------------------------------------
__global__ __launch_bounds__(256, 8) void conv_kernel(
    const float* __restrict__ x, float* __restrict__ ws)
{
    __shared__ __align__(16) float s_x[16][20];        //  1280 B
    __shared__ __align__(16) float s_h1[16][14][20];   // 17920 B
    __shared__ float s_h2[16 * 156];                   //  9984 B (stride-13 rows)

    const int b = blockIdx.x;
    const int t = threadIdx.x;

    // ---- Stage A: input act-quant (accumulation-free -> hard round) ----
    {
        const float v = x[b * 256 + t];
        float m = fabsf(v);
        #pragma unroll
        for (int msk = 8; msk >= 1; msk >>= 1) m = fmaxf(m, __shfl_xor(m, msk, 16));
        const float s = __fdiv_rn(127.0f, fmaxf(m, 1e-5f));
        float q = rintf(__fmul_rn(v, s));
        q = fminf(fmaxf(q, -128.f), 127.f);
        s_x[t >> 4][t & 15] = __fdiv_rn(q, s);
    }
    __syncthreads();

    // ---- Stage B: conv1 (1->16, 3x3) + ReLU + row quant ----
    if (t < 224) {
        const int oc = t / 14, oh = t % 14;
        const float* __restrict__ wg = ws + OFF_W1 + oc * 12;
        const float4 wv0 = *(const float4*)&wg[0];
        const float4 wv1 = *(const float4*)&wg[4];
        const float  w8  = wg[8];
        const float wr[9] = {wv0.x, wv0.y, wv0.z, wv0.w,
                             wv1.x, wv1.y, wv1.z, wv1.w, w8};
        float acc[14];
        #pragma unroll
        for (int ow = 0; ow < 14; ++ow) acc[ow] = 0.f;
        #pragma unroll
        for (int kh = 0; kh < 3; ++kh) {
            float A[16];
            *(float4*)&A[0]  = *(const float4*)&s_x[oh + kh][0];
            *(float4*)&A[4]  = *(const float4*)&s_x[oh + kh][4];
            *(float4*)&A[8]  = *(const float4*)&s_x[oh + kh][8];
            *(float4*)&A[12] = *(const float4*)&s_x[oh + kh][12];
            #pragma unroll
            for (int kw = 0; kw < 3; ++kw) {
                const float wk = wr[kh * 3 + kw];
                #pragma unroll
                for (int ow = 0; ow < 14; ++ow)
                    acc[ow] = __fmaf_rn(A[ow + kw], wk, acc[ow]);
            }
        }
        float mx = 0.f;
        #pragma unroll
        for (int ow = 0; ow < 14; ++ow) { acc[ow] = fmaxf(acc[ow], 0.f); mx = fmaxf(mx, acc[ow]); }
        const float s = __fdiv_rn(127.0f, fmaxf(mx, 1e-5f));
        float q[14];
        #pragma unroll
        for (int ow = 0; ow < 14; ++ow) q[ow] = quantq(acc[ow], s);
        *(float4*)&s_h1[oc][oh][0]  = *(const float4*)&q[0];
        *(float4*)&s_h1[oc][oh][4]  = *(const float4*)&q[4];
        *(float4*)&s_h1[oc][oh][8]  = *(const float4*)&q[8];
        *(float2*)&s_h1[oc][oh][12] = *(const float2*)&q[12];
    }
    __syncthreads();

    // ---- Stage C: conv1b (16->16, 3x3) + ReLU + row quant ----
    if (t < 192) {
        const int oc = t / 12, oh = t % 12;
        const float* __restrict__ wg = ws + OFF_W1B + oc * 192;
        float acc[12];
        #pragma unroll
        for (int i = 0; i < 12; ++i) acc[i] = 0.f;
        for (int ic = 0; ic < 16; ++ic) {
            const float4 wv0 = *(const float4*)&wg[ic * 12];
            const float4 wv1 = *(const float4*)&wg[ic * 12 + 4];
            const float  w8  = wg[ic * 12 + 8];
            const float wr[9] = {wv0.x, wv0.y, wv0.z, wv0.w,
                                 wv1.x, wv1.y, wv1.z, wv1.w, w8};
            #pragma unroll
            for (int kh = 0; kh < 3; ++kh) {
                float A[14];
                *(float4*)&A[0]  = *(const float4*)&s_h1[ic][oh + kh][0];
                *(float4*)&A[4]  = *(const float4*)&s_h1[ic][oh + kh][4];
                *(float4*)&A[8]  = *(const float4*)&s_h1[ic][oh + kh][8];
                *(float2*)&A[12] = *(const float2*)&s_h1[ic][oh + kh][12];
                #pragma unroll
                for (int kw = 0; kw < 3; ++kw) {
                    const float w = wr[kh * 3 + kw];
                    #pragma unroll
                    for (int ow = 0; ow < 12; ++ow)
                        acc[ow] = __fmaf_rn(A[ow + kw], w, acc[ow]);
                }
            }
        }
        float mx = 0.f;
        #pragma unroll
        for (int ow = 0; ow < 12; ++ow) { acc[ow] = fmaxf(acc[ow], 0.f); mx = fmaxf(mx, acc[ow]); }
        const float s = __fdiv_rn(127.0f, fmaxf(mx, 1e-5f));
        const int hb = oc * 156 + oh * 13;
        #pragma unroll
        for (int ow = 0; ow < 12; ++ow)
            s_h2[hb + ow] = quantq(acc[ow], s);
    }
    __syncthreads();

    // ---- Stage D: conv2 grouped binary (16 g x 6 oc, 12x12) + ReLU ----
    if (t < 96) {
        const int g = t / 6;
        const float* __restrict__ wp = ws + OFF_W2;  // [k=144][96 oc]
        float acc = 0.f;
        #pragma unroll
        for (int r = 0; r < 12; ++r) {
            const int hb = g * 156 + r * 13;
            #pragma unroll
            for (int c = 0; c < 12; ++c)
                acc = __fmaf_rn(s_h2[hb + c], wp[(r * 12 + c) * 96 + t], acc);
        }
        ws[OFF_V96 + b * 96 + t] = fmaxf(acc, 0.f);   // global handoff
    }
}

// ---------------------------------------------------------------------------
// fc_kernel: 4 waves per block, each wave owns one image; mean-reduce done
// in-register via bpermute/shfl chains preserving the exact numpy-pairwise
// order. LDS 1,536 B.
// ---------------------------------------------------------------------------
__global__ __launch_bounds__(256) void fc_kernel(
    const float* __restrict__ ws, float* __restrict__ out, int nimg)
{
    __shared__ float s_q[4][96];

    const int t = threadIdx.x;
    const int w = t >> 6;      // wave id = image slot
    const int l = t & 63;      // lane within wave
    const int j = l & 7;       // r8 slot this lane reproduces
    const int img = blockIdx.x * 4 + w;
    if (img >= nimg) return;

    const float* __restrict__ v96 = ws + OFF_V96 + img * 96;

    // ---- Stage E: fc1 (96->64) ----
    float u;   // current activation vector element (lane l holds element l)
    {
        const float va = v96[l];
        const float vb = (l < 32) ? v96[64 + l] : 0.f;
        const float asq = __fmul_rn(va, va);     // t96[l]
        const float bsq = __fmul_rn(vb, vb);     // t96[64+l] (valid l<32)
        // r8[j] = t[j] + t[j+8] + ... + t[j+88], serial left-assoc (exact order):
        float r = __shfl(asq, j, 64);
        #pragma unroll
        for (int m2 = 1; m2 < 8; ++m2) r = __fadd_rn(r, __shfl(asq, j + 8 * m2, 64));
        #pragma unroll
        for (int m2 = 0; m2 < 4; ++m2) r = __fadd_rn(r, __shfl(bsq, j + 8 * m2, 64));
        // c = ((r0+r1)+(r2+r3)) + ((r4+r5)+(r6+r7)) via commutative butterfly:
        float c = __fadd_rn(r, __shfl_xor(r, 1, 64));
        c = __fadd_rn(c, __shfl_xor(c, 2, 64));
        c = __fadd_rn(c, __shfl_xor(c, 4, 64));
        const float mean = __fdiv_rn(c, 96.0f);
        const float bc1 = __fdiv_rn(1.0f, __fsqrt_rn(__fadd_rn(mean, 1e-6f)));
        const float n0 = __fmul_rn(va, bc1);
        const float n1 = __fmul_rn(vb, bc1);       // valid for l<32
        float m = n0;
        if (l < 32) m = fmaxf(m, n1);
        #pragma unroll
        for (int msk = 32; msk >= 1; msk >>= 1) m = fmaxf(m, __shfl_xor(m, msk, 64));
        const float s2 = __fdiv_rn(127.0f, fmaxf(m, 1e-5f));
        s_q[w][l] = quantq(n0, s2);
        if (l < 32) s_q[w][64 + l] = quantq(n1, s2);
        const float* __restrict__ wp = ws + OFF_F1;  // [k=96][64 o]
        float acc = 0.f;
        for (int k = 0; k < 96; ++k) acc = __fmaf_rn(s_q[w][k], wp[k * 64 + l], acc);
        u = fmaxf(acc, 0.f);
    }

    // ---- Stages F,G: fc2, fc3 (64->64) ----
    #pragma unroll 1
    for (int stage = 0; stage < 2; ++stage) {
        const int woff = stage == 0 ? OFF_F2 : OFF_F3;
        const float usq = __fmul_rn(u, u);
        // r8[j] = t[j] + t[j+8] + ... + t[j+56], serial left-assoc:
        float r = __shfl(usq, j, 64);
        #pragma unroll
        for (int m2 = 1; m2 < 8; ++m2) r = __fadd_rn(r, __shfl(usq, j + 8 * m2, 64));
        float c = __fadd_rn(r, __shfl_xor(r, 1, 64));
        c = __fadd_rn(c, __shfl_xor(c, 2, 64));
        c = __fadd_rn(c, __shfl_xor(c, 4, 64));
        const float mean = __fdiv_rn(c, 64.0f);
        const float bc1 = __fdiv_rn(1.0f, __fsqrt_rn(__fadd_rn(mean, 1e-6f)));
        const float n0 = __fmul_rn(u, bc1);
        float m = n0;
        #pragma unroll
        for (int msk = 32; msk >= 1; msk >>= 1) m = fmaxf(m, __shfl_xor(m, msk, 64));
        const float s2 = __fdiv_rn(127.0f, fmaxf(m, 1e-5f));
        s_q[w][l] = quantq(n0, s2);
        const float* __restrict__ wp = ws + woff;    // [k=64][64 o]
        float acc = 0.f;
        for (int k = 0; k < 64; ++k) acc = __fmaf_rn(s_q[w][k], wp[k * 64 + l], acc);
        u = fmaxf(acc, 0.f);
    }

    // ---- Stage H: fcl (64->10), no ReLU ----
    {
        const float usq = __fmul_rn(u, u);
        float r = __shfl(usq, j, 64);
        #pragma unroll
        for (int m2 = 1; m2 < 8; ++m2) r = __fadd_rn(r, __shfl(usq, j + 8 * m2, 64));
        float c = __fadd_rn(r, __shfl_xor(r, 1, 64));
        c = __fadd_rn(c, __shfl_xor(c, 2, 64));
        c = __fadd_rn(c, __shfl_xor(c, 4, 64));
        const float mean = __fdiv_rn(c, 64.0f);
        const float bc1 = __fdiv_rn(1.0f, __fsqrt_rn(__fadd_rn(mean, 1e-6f)));
        const float n0 = __fmul_rn(u, bc1);
        float m = n0;
        #pragma unroll
        for (int msk = 32; msk >= 1; msk >>= 1) m = fmaxf(m, __shfl_xor(m, msk, 64));
        const float s2 = __fdiv_rn(127.0f, fmaxf(m, 1e-5f));
        s_q[w][l] = quantq(n0, s2);
        const int to = (l < 10) ? l : 9;             // clamp: avoid OOB reads
        const float* __restrict__ wp = ws + OFF_FL;  // [k=64][10 o]
        float acc = 0.f;
        for (int k = 0; k < 64; ++k) acc = __fmaf_rn(s_q[w][k], wp[k * 10 + to], acc);
        if (l < 10) out[img * 10 + l] = acc;
    }
}

extern "C" void kernel_launch(void* const* d_in, const int* in_sizes, int n_in,
                              void* d_out, int out_size, void* d_ws, size_t ws_size,
                              hipStream_t stream) {
    const float* x   = (const float*)d_in[0];
    const float* w1  = (const float*)d_in[1];
    const float* w1b = (const float*)d_in[2];
    const float* w2  = (const float*)d_in[3];
    const float* f1  = (const float*)d_in[4];
    const float* f2  = (const float*)d_in[5];
    const float* f3  = (const float*)d_in[6];
    const float* fl  = (const float*)d_in[7];
    float* out = (float*)d_out;
    float* ws  = (float*)d_ws;

    const int B = in_sizes[0] / 256;  // 8192

    wq_kernel<<<7, 256, 0, stream>>>(w1, w1b, w2, f1, f2, f3, fl, ws);
    conv_kernel<<<B, 256, 0, stream>>>(x, ws);
    fc_kernel<<<(B + 3) / 4, 256, 0, stream>>>(ws, out, B);
}